// Round 1
// 74.320 us; speedup vs baseline: 1.0235x; 1.0235x over previous
//
#include <hip/hip_runtime.h>
#include <math.h>

// CompetingRisks: B=4096, D=128, R=2.  (R12 = R11 with 512-thread blocks)
// K0 prologue: pre-convert w1 -> bf16 hi/lo in MFMA A-FRAGMENT ORDER in d_ws,
//   and pack A/C/W/b1 contiguously.  Runs every call (graph-safe).
// K1 main: per block (16 tasks, one r): 512 threads = 8 waves:
//   Phase A: 8 waves split 17 j-strips (coalesced A-frag loads + 12 MFMAs each)
//   Phase B: fixed-step RK4 (2 steps, h=0.5), 32 lanes/task (NU=9),
//   DPP reduce within 16 + one shfl_xor(16) step.
// Rationale: grid 512 was occupancy-limited (2 blk/CU = 2 waves/SIMD); 512-thread
//   blocks with __launch_bounds__(512,4) give 16 waves/CU to hide cold-L2 frag
//   load latency (poison fill flushes L3 every iter) and Phase-B serial tails.

#define B_ 4096
#define R_ 2
#define D_ 128
#define IN_ 130
#define HID_ 260
#define NU_ 9         // units per lane: j = sub + 32*i  (covers 288 >= 272)
#define KP_ 136       // LDS z row pitch (shorts): 128 + 8 pad
#define PPW_ 272      // ws ACW row pitch (floats) -- k0 layout
#define PPL_ 292      // LDS P/ACW row pitch (floats): >=288, mod 32 == 4 (bank spread)

// ws layout: shorts [AFH_ | AFL_] then floats [ACWF_]
#define AFH_   0                       // 81920 shorts: [r][c5][s4][ks4][lane64][8]
#define AFL_   81920
#define ACWF_  81920                   // FLOAT offset = byte 327680; [r][4][272]

typedef __attribute__((ext_vector_type(8))) short  short8;
typedef __attribute__((ext_vector_type(4))) float  floatx4;

__device__ __forceinline__ unsigned short f2bf_rn(float x) {
    unsigned int u = __float_as_uint(x);
    unsigned int r = (u + 0x7FFFu + ((u >> 16) & 1u)) >> 16;
    return (unsigned short)r;
}
__device__ __forceinline__ float bf2f(unsigned short h) {
    return __uint_as_float(((unsigned int)h) << 16);
}

// ---------------- K0: pack w fragments + ACW (unchanged) ----------------
__global__ __launch_bounds__(256) void k0_pack(
    const float* __restrict__ w1, const float* __restrict__ b1,
    const float* __restrict__ w2, float* __restrict__ wsf)
{
    unsigned short* wss = (unsigned short*)wsf;
    const int gid = blockIdx.x * 256 + threadIdx.x;

    if (gid < 10240) {
        const int l  = gid & 63;
        const int ks = (gid >> 6) & 3;
        const int s  = (gid >> 8) & 3;
        const int rc = gid >> 10;            // r*5 + c
        const int r  = rc / 5;
        const int c  = rc % 5;
        const int j  = c * 64 + s * 16 + (l & 15);
        const int k  = ks * 32 + (l >> 4) * 8;
        float v[8];
        if (j < HID_) {
            const float* src = w1 + (r * HID_ + j) * IN_ + 2 + k;  // 8B-aligned
#pragma unroll
            for (int e = 0; e < 8; e += 2) {
                const float2 p = *(const float2*)(src + e);
                v[e] = p.x; v[e + 1] = p.y;
            }
        } else {
#pragma unroll
            for (int e = 0; e < 8; ++e) v[e] = 0.f;
        }
        short8 hi, lo;
#pragma unroll
        for (int e = 0; e < 8; ++e) {
            const unsigned short h = f2bf_rn(v[e]);
            hi[e] = (short)h;
            lo[e] = (short)f2bf_rn(v[e] - bf2f(h));
        }
        *(short8*)(wss + AFH_ + gid * 8) = hi;
        *(short8*)(wss + AFL_ + gid * 8) = lo;
    } else {
        const int idx = gid - 10240;         // ACW+b1 pack: 544 entries
        if (idx < 544) {
            const int r = idx / PPW_;
            const int j = idx % PPW_;
            float av = 0.f, cv = 0.f, wv = 0.f, bv = 0.f;
            if (j < HID_) {
                const float2 ac = *(const float2*)(w1 + (r * HID_ + j) * IN_);
                av = ac.x; cv = ac.y;
                wv = w2[r * HID_ + j];
                bv = b1[r * HID_ + j];
            }
            float* acw = wsf + ACWF_ + r * 4 * PPW_;
            acw[0 * PPW_ + j] = av;
            acw[1 * PPW_ + j] = cv;
            acw[2 * PPW_ + j] = wv;
            acw[3 * PPW_ + j] = bv;
        }
    }
}

// ---------------- K1: MFMA P + RK4 solve ----------------
__device__ __forceinline__ float dpp_add16(float v) {
    int y;
    y = __builtin_amdgcn_update_dpp(0, __float_as_int(v), 0xB1, 0xF, 0xF, false);  // quad xor1
    v += __int_as_float(y);
    y = __builtin_amdgcn_update_dpp(0, __float_as_int(v), 0x4E, 0xF, 0xF, false);  // quad xor2
    v += __int_as_float(y);
    y = __builtin_amdgcn_update_dpp(0, __float_as_int(v), 0x124, 0xF, 0xF, false); // row_ror:4
    v += __int_as_float(y);
    y = __builtin_amdgcn_update_dpp(0, __float_as_int(v), 0x128, 0xF, 0xF, false); // row_ror:8
    v += __int_as_float(y);
    return v;
}

__device__ __forceinline__ float softplus_fast(float x) {
    const float q  = exp2f(-1.4426950408889634f * fabsf(x));
    const float lg = 0.6931471805599453f * log2f(1.0f + q);
    return fmaxf(x, 0.0f) + lg;
}

__global__ __launch_bounds__(512, 4) void cr_main(
    const float* __restrict__ z, const float* __restrict__ t_eval,
    const float* __restrict__ b2, const float* __restrict__ wsf,
    float* __restrict__ out)
{
    __shared__ unsigned short sZh[16 * KP_];
    __shared__ unsigned short sZl[16 * KP_];
    __shared__ float sP[16 * PPL_];
    __shared__ float sACW[4 * PPL_];           // ~32 KB total

    const int t  = threadIdx.x;
    const int r  = blockIdx.x >> 8;
    const int b0 = (blockIdx.x & 255) * 16;

    // ---- stage ACW (coalesced from ws), zero-pad cols [272,292) ----
#pragma unroll
    for (int p = 0; p < 3; ++p) {
        const int i = p * 512 + t;
        if (i < 4 * PPL_) {
            const int a  = i / PPL_;
            const int jj = i - a * PPL_;
            sACW[i] = (jj < PPW_) ? wsf[ACWF_ + (r * 4 + a) * PPW_ + jj] : 0.f;
        }
    }
    // ---- zero sP pad columns [272,292) (Phase B reads j<288; avoid NaN*0) ----
    if (t < 320) {
        const int row = t / 20;
        const int col = t - row * 20;
        sP[row * PPL_ + PPW_ + col] = 0.f;
    }

    // ---- stage z tile: 16 rows x 128, hi/lo bf16; one float4 per thread ----
    {
        const int row = t >> 5;
        const int c0  = (t & 31) * 4;
        const float4 v = *(const float4*)(z + (b0 + row) * D_ + c0);
        unsigned short* dh = sZh + row * KP_ + c0;
        unsigned short* dl = sZl + row * KP_ + c0;
        const unsigned short h0 = f2bf_rn(v.x); const float p0 = v.x - bf2f(h0);
        const unsigned short h1 = f2bf_rn(v.y); const float p1 = v.y - bf2f(h1);
        const unsigned short h2 = f2bf_rn(v.z); const float p2 = v.z - bf2f(h2);
        const unsigned short h3 = f2bf_rn(v.w); const float p3 = v.w - bf2f(h3);
        *(short4*)dh = make_short4((short)h0, (short)h1, (short)h2, (short)h3);
        *(short4*)dl = make_short4((short)f2bf_rn(p0), (short)f2bf_rn(p1),
                                   (short)f2bf_rn(p2), (short)f2bf_rn(p3));
    }
    __syncthreads();

    // ---- Phase A: 17 j-strips over 8 waves; A-frags direct from ws ----
    const int wv_  = t >> 6;                   // 0..7
    const int lane = t & 63;
    const int lm   = lane & 15;
    const int quad = lane >> 4;
    const unsigned short* wss = (const unsigned short*)wsf;

    for (int S = wv_; S < 17; S += 8) {        // strip S covers j in [S*16, S*16+16)
        floatx4 acc = {0.f, 0.f, 0.f, 0.f};
        const int fb = ((r * 20 + S) * 4) * 512 + lane * 8;   // frag gid*8
        const unsigned short* afh = wss + AFH_ + fb;
        const unsigned short* afl = wss + AFL_ + fb;
        const unsigned short* bph = sZh + lm * KP_ + quad * 8;
        const unsigned short* bpl = sZl + lm * KP_ + quad * 8;
#pragma unroll
        for (int ks = 0; ks < 4; ++ks) {
            const short8 Ah = *(const short8*)(afh + ks * 512);
            const short8 Al = *(const short8*)(afl + ks * 512);
            const short8 Bh = *(const short8*)(bph + ks * 32);
            const short8 Bl = *(const short8*)(bpl + ks * 32);
            acc = __builtin_amdgcn_mfma_f32_16x16x32_bf16(Ah, Bh, acc, 0, 0, 0);
            acc = __builtin_amdgcn_mfma_f32_16x16x32_bf16(Ah, Bl, acc, 0, 0, 0);
            acc = __builtin_amdgcn_mfma_f32_16x16x32_bf16(Al, Bh, acc, 0, 0, 0);
        }
        float4 o;
        o.x = acc[0]; o.y = acc[1]; o.z = acc[2]; o.w = acc[3];
        *(float4*)(sP + lm * PPL_ + S * 16 + quad * 4) = o;
    }
    __syncthreads();

    // ---- Phase B: RK4 (2 steps, h=0.5), 32 lanes/task ----
    const int sub = t & 31;
    const int g   = t >> 5;
    const int b   = b0 + g;
    const float te = t_eval[b];

    const float* sA  = sACW;
    const float* sC  = sACW + PPL_;
    const float* sWo = sACW + 2 * PPL_;
    const float* sB1 = sACW + 3 * PPL_;

    float P[NU_], A[NU_], C[NU_], W[NU_];
    const float* pg = sP + g * PPL_;
#pragma unroll
    for (int i = 0; i < NU_; ++i) {
        const int j = sub + (i << 5);
        P[i] = pg[j] + sB1[j];
        A[i] = sA[j];
        C[i] = sC[j];
        W[i] = sWo[j];
    }
    const float b2r = b2[r];

    auto feval = [&](float t1, float yv) -> float {
        const float tt = t1 * te;
        float d0 = 0.f, d1 = 0.f;
#pragma unroll
        for (int i = 0; i < NU_; ++i) {
            const float hv = fmaf(tt, A[i], fmaf(yv, C[i], P[i]));
            if (i & 1) d1 = fmaf(W[i], fmaxf(hv, 0.f), d1);
            else       d0 = fmaf(W[i], fmaxf(hv, 0.f), d0);
        }
        float dot = dpp_add16(d0 + d1);
        dot += __shfl_xor(dot, 16, 64);        // fold across the two 16-lane rows
        return softplus_fast(dot + b2r) * te;
    };

    const float h  = 0.5f;
    const float hh = 0.25f;
    float y = 0.f;
#pragma unroll 1
    for (int s = 0; s < 2; ++s) {
        const float t0 = (float)s * h;
        const float k1 = feval(t0,      y);
        const float k2 = feval(t0 + hh, fmaf(hh, k1, y));
        const float k3 = feval(t0 + hh, fmaf(hh, k2, y));
        const float k4 = feval(t0 + h,  fmaf(h,  k3, y));
        y = fmaf(h * (1.f / 6.f), k1 + 2.f * (k2 + k3) + k4, y);
    }

    const float yT = y;
    const float hazf = feval(1.0f, yT);
    const float t_rec = (te != 0.f) ? (1.f / te) : 0.f;

    if (sub == 0) {
        out[r * B_ + b] = t_rec * hazf;               // haz: [R,1,B]
        const int base = R_ * B_ + (r * B_ + b) * 2;  // chf: [R,B,2,1]
        out[base + 0] = 0.f;
        out[base + 1] = yT;
    }
}

extern "C" void kernel_launch(void* const* d_in, const int* in_sizes, int n_in,
                              void* d_out, int out_size, void* d_ws, size_t ws_size,
                              hipStream_t stream) {
    const float* z      = (const float*)d_in[0];
    const float* t_eval = (const float*)d_in[1];
    const float* w1     = (const float*)d_in[2];
    const float* b1     = (const float*)d_in[3];
    const float* w2     = (const float*)d_in[4];
    const float* b2     = (const float*)d_in[5];
    float* out = (float*)d_out;
    float* ws  = (float*)d_ws;   // ~337 KB used

    hipLaunchKernelGGL(k0_pack, dim3(43),  dim3(256), 0, stream, w1, b1, w2, ws);
    hipLaunchKernelGGL(cr_main, dim3(512), dim3(512), 0, stream, z, t_eval, b2, ws, out);
}

// Round 2
// 72.247 us; speedup vs baseline: 1.0529x; 1.0287x over previous
//
#include <hip/hip_runtime.h>
#include <math.h>

// CompetingRisks: B=4096, D=128, R=2.  (R13 = R12 with k0_pack fused away)
// Single kernel: per block (16 tasks, one r), 512 threads = 8 waves:
//   Prologue: gather A/C/W/b1 coeffs from w1/b1/w2 into LDS; stage z tile hi/lo.
//   Phase A: 8 waves split 17 j-strips. Each wave loads its strip's w1 rows
//     DIRECTLY from global (16 rows x 8 floats/lane as float2), splits to
//     bf16 hi/lo in registers via truncation split (hi = bits>>16,
//     lo = trunc16(v - hi<<16); combined rel err ~2^-14, sub-dominant), and
//     runs 12 MFMAs -> P in LDS.  This removes k0_pack (tiny latency-bound
//     prologue kernel), one launch gap, and the 337 KB ws round-trip.
//   Phase B: fixed-step RK4 (2 steps, h=0.5), 32 lanes/task (NU=9),
//     DPP reduce within 16 + one shfl_xor(16) step.
// Error budget: dopri5's embedded error IS the 4th-order term -> RK4@h=0.5
//   local err ~2e-3, global ~4e-3, << 0.115 threshold.

#define B_ 4096
#define R_ 2
#define D_ 128
#define IN_ 130
#define HID_ 260
#define NU_ 9         // units per lane: j = sub + 32*i  (covers 288 >= 272)
#define KP_ 136       // LDS z row pitch (shorts): 128 + 8 pad
#define PPL_ 292      // LDS P/ACW row pitch (floats): >=288, mod 32 == 4

typedef __attribute__((ext_vector_type(8))) short  short8;
typedef __attribute__((ext_vector_type(4))) float  floatx4;

__device__ __forceinline__ unsigned short f2bf_rn(float x) {
    unsigned int u = __float_as_uint(x);
    unsigned int r = (u + 0x7FFFu + ((u >> 16) & 1u)) >> 16;
    return (unsigned short)r;
}
__device__ __forceinline__ float bf2f(unsigned short h) {
    return __uint_as_float(((unsigned int)h) << 16);
}

__device__ __forceinline__ float dpp_add16(float v) {
    int y;
    y = __builtin_amdgcn_update_dpp(0, __float_as_int(v), 0xB1, 0xF, 0xF, false);  // quad xor1
    v += __int_as_float(y);
    y = __builtin_amdgcn_update_dpp(0, __float_as_int(v), 0x4E, 0xF, 0xF, false);  // quad xor2
    v += __int_as_float(y);
    y = __builtin_amdgcn_update_dpp(0, __float_as_int(v), 0x124, 0xF, 0xF, false); // row_ror:4
    v += __int_as_float(y);
    y = __builtin_amdgcn_update_dpp(0, __float_as_int(v), 0x128, 0xF, 0xF, false); // row_ror:8
    v += __int_as_float(y);
    return v;
}

__device__ __forceinline__ float softplus_fast(float x) {
    const float q  = exp2f(-1.4426950408889634f * fabsf(x));
    const float lg = 0.6931471805599453f * log2f(1.0f + q);
    return fmaxf(x, 0.0f) + lg;
}

__global__ __launch_bounds__(512, 4) void cr_main(
    const float* __restrict__ z, const float* __restrict__ t_eval,
    const float* __restrict__ w1, const float* __restrict__ b1,
    const float* __restrict__ w2, const float* __restrict__ b2,
    float* __restrict__ out)
{
    __shared__ unsigned short sZh[16 * KP_];
    __shared__ unsigned short sZl[16 * KP_];
    __shared__ float sP[16 * PPL_];
    __shared__ float sACW[4 * PPL_];           // ~32 KB total

    const int t  = threadIdx.x;
    const int r  = blockIdx.x >> 8;
    const int b0 = (blockIdx.x & 255) * 16;

    // ---- gather ACW (A=w1[:,0], C=w1[:,1], W=w2, B1=b1) into LDS ----
    if (t < PPL_) {
        const int j = t;
        float av = 0.f, cv = 0.f, wv = 0.f, bv = 0.f;
        if (j < HID_) {
            const float2 ac = *(const float2*)(w1 + (size_t)(r * HID_ + j) * IN_);
            av = ac.x; cv = ac.y;
            wv = w2[r * HID_ + j];
            bv = b1[r * HID_ + j];
        }
        sACW[0 * PPL_ + j] = av;
        sACW[1 * PPL_ + j] = cv;
        sACW[2 * PPL_ + j] = wv;
        sACW[3 * PPL_ + j] = bv;
    }
    // ---- zero sP pad columns [272,292) (Phase B reads j<288) ----
    if (t < 320) {
        const int row = t / 20;
        const int col = t - row * 20;
        sP[row * PPL_ + 272 + col] = 0.f;
    }

    // ---- stage z tile: 16 rows x 128, hi/lo bf16; one float4 per thread ----
    {
        const int row = t >> 5;
        const int c0  = (t & 31) * 4;
        const float4 v = *(const float4*)(z + (b0 + row) * D_ + c0);
        unsigned short* dh = sZh + row * KP_ + c0;
        unsigned short* dl = sZl + row * KP_ + c0;
        const unsigned short h0 = f2bf_rn(v.x); const float p0 = v.x - bf2f(h0);
        const unsigned short h1 = f2bf_rn(v.y); const float p1 = v.y - bf2f(h1);
        const unsigned short h2 = f2bf_rn(v.z); const float p2 = v.z - bf2f(h2);
        const unsigned short h3 = f2bf_rn(v.w); const float p3 = v.w - bf2f(h3);
        *(short4*)dh = make_short4((short)h0, (short)h1, (short)h2, (short)h3);
        *(short4*)dl = make_short4((short)f2bf_rn(p0), (short)f2bf_rn(p1),
                                   (short)f2bf_rn(p2), (short)f2bf_rn(p3));
    }
    __syncthreads();

    // ---- Phase A: 17 j-strips over 8 waves; A from w1 direct, convert in reg ----
    const int wv_  = t >> 6;                   // 0..7
    const int lane = t & 63;
    const int jl   = lane & 15;                // A row within strip == P task col
    const int quad = lane >> 4;
    const float* w1r = w1 + (size_t)r * HID_ * IN_;

    for (int S = wv_; S < 17; S += 8) {        // strip S covers j in [S*16, S*16+16)
        const int j = S * 16 + jl;
        float2 L[16];
        if (j < HID_) {
            const float* src = w1r + j * IN_ + 2 + quad * 8;
#pragma unroll
            for (int ks = 0; ks < 4; ++ks)
#pragma unroll
                for (int e = 0; e < 4; ++e)
                    L[ks * 4 + e] = *(const float2*)(src + ks * 32 + e * 2);
        } else {
#pragma unroll
            for (int i = 0; i < 16; ++i) L[i] = make_float2(0.f, 0.f);
        }

        floatx4 acc = {0.f, 0.f, 0.f, 0.f};
        const unsigned short* bph = sZh + jl * KP_ + quad * 8;
        const unsigned short* bpl = sZl + jl * KP_ + quad * 8;
#pragma unroll
        for (int ks = 0; ks < 4; ++ks) {
            short8 Ah, Al;
#pragma unroll
            for (int e = 0; e < 4; ++e) {
                const float2 p = L[ks * 4 + e];
                const unsigned int ux = __float_as_uint(p.x);
                const unsigned int uy = __float_as_uint(p.y);
                Ah[2 * e]     = (short)(ux >> 16);
                Ah[2 * e + 1] = (short)(uy >> 16);
                const float rx = p.x - __uint_as_float(ux & 0xFFFF0000u);
                const float ry = p.y - __uint_as_float(uy & 0xFFFF0000u);
                Al[2 * e]     = (short)(__float_as_uint(rx) >> 16);
                Al[2 * e + 1] = (short)(__float_as_uint(ry) >> 16);
            }
            const short8 Bh = *(const short8*)(bph + ks * 32);
            const short8 Bl = *(const short8*)(bpl + ks * 32);
            acc = __builtin_amdgcn_mfma_f32_16x16x32_bf16(Ah, Bh, acc, 0, 0, 0);
            acc = __builtin_amdgcn_mfma_f32_16x16x32_bf16(Ah, Bl, acc, 0, 0, 0);
            acc = __builtin_amdgcn_mfma_f32_16x16x32_bf16(Al, Bh, acc, 0, 0, 0);
        }
        float4 o;
        o.x = acc[0]; o.y = acc[1]; o.z = acc[2]; o.w = acc[3];
        *(float4*)(sP + jl * PPL_ + S * 16 + quad * 4) = o;
    }
    __syncthreads();

    // ---- Phase B: RK4 (2 steps, h=0.5), 32 lanes/task ----
    const int sub = t & 31;
    const int g   = t >> 5;
    const int b   = b0 + g;
    const float te = t_eval[b];

    const float* sA  = sACW;
    const float* sC  = sACW + PPL_;
    const float* sWo = sACW + 2 * PPL_;
    const float* sB1 = sACW + 3 * PPL_;

    float P[NU_], A[NU_], C[NU_], W[NU_];
    const float* pg = sP + g * PPL_;
#pragma unroll
    for (int i = 0; i < NU_; ++i) {
        const int j = sub + (i << 5);
        P[i] = pg[j] + sB1[j];
        A[i] = sA[j];
        C[i] = sC[j];
        W[i] = sWo[j];
    }
    const float b2r = b2[r];

    auto feval = [&](float t1, float yv) -> float {
        const float tt = t1 * te;
        float d0 = 0.f, d1 = 0.f;
#pragma unroll
        for (int i = 0; i < NU_; ++i) {
            const float hv = fmaf(tt, A[i], fmaf(yv, C[i], P[i]));
            if (i & 1) d1 = fmaf(W[i], fmaxf(hv, 0.f), d1);
            else       d0 = fmaf(W[i], fmaxf(hv, 0.f), d0);
        }
        float dot = dpp_add16(d0 + d1);
        dot += __shfl_xor(dot, 16, 64);        // fold across the two 16-lane rows
        return softplus_fast(dot + b2r) * te;
    };

    const float h  = 0.5f;
    const float hh = 0.25f;
    float y = 0.f;
#pragma unroll 1
    for (int s = 0; s < 2; ++s) {
        const float t0 = (float)s * h;
        const float k1 = feval(t0,      y);
        const float k2 = feval(t0 + hh, fmaf(hh, k1, y));
        const float k3 = feval(t0 + hh, fmaf(hh, k2, y));
        const float k4 = feval(t0 + h,  fmaf(h,  k3, y));
        y = fmaf(h * (1.f / 6.f), k1 + 2.f * (k2 + k3) + k4, y);
    }

    const float yT = y;
    const float hazf = feval(1.0f, yT);
    const float t_rec = (te != 0.f) ? (1.f / te) : 0.f;

    if (sub == 0) {
        out[r * B_ + b] = t_rec * hazf;               // haz: [R,1,B]
        const int base = R_ * B_ + (r * B_ + b) * 2;  // chf: [R,B,2,1]
        out[base + 0] = 0.f;
        out[base + 1] = yT;
    }
}

extern "C" void kernel_launch(void* const* d_in, const int* in_sizes, int n_in,
                              void* d_out, int out_size, void* d_ws, size_t ws_size,
                              hipStream_t stream) {
    const float* z      = (const float*)d_in[0];
    const float* t_eval = (const float*)d_in[1];
    const float* w1     = (const float*)d_in[2];
    const float* b1     = (const float*)d_in[3];
    const float* w2     = (const float*)d_in[4];
    const float* b2     = (const float*)d_in[5];
    float* out = (float*)d_out;
    (void)d_ws; (void)ws_size;

    hipLaunchKernelGGL(cr_main, dim3(512), dim3(512), 0, stream,
                       z, t_eval, w1, b1, w2, b2, out);
}